// Round 3
// baseline (915.877 us; speedup 1.0000x reference)
//
#include <hip/hip_runtime.h>

// Quantizer: B=8, N=4096, D=64, K=8192
// probs = softmax(sim/T) over K;  z_q = probs @ codebook
// sim = l2norm(z) @ l2norm(emb)^T, sim in [-1,1] -> no online max needed.
// Round 3: kill the 684us hipMemsetAsync (rocclr fill was 12.5 GB/s!) by
// replacing atomic accumulation with per-K-chunk partial buffers + tree
// reduce. No memset, no atomics -> deterministic.

#define M_TOTAL 32768   // B*N
#define KCODES  8192
#define DDIM    64
#define KSPLIT  4
#define KCHUNK  (KCODES / KSPLIT)   // 2048

typedef __attribute__((ext_vector_type(8))) short bf16x8;
typedef __attribute__((ext_vector_type(4))) short bf16x4;
typedef __attribute__((ext_vector_type(4))) float f32x4;

__device__ inline unsigned short f2bf(float x) {
  union { float f; unsigned u; } v; v.f = x;
  unsigned r = v.u + 0x7FFFu + ((v.u >> 16) & 1u);  // RNE
  return (unsigned short)(r >> 16);
}

// One wave per row: L2-normalize, emit bf16 (and optional transposed copy).
__global__ __launch_bounds__(256) void norm_rows_kernel(
    const float* __restrict__ in, unsigned short* __restrict__ out,
    unsigned short* __restrict__ outT, int nrows, int tstride) {
  int row = blockIdx.x * 4 + (threadIdx.x >> 6);
  int lane = threadIdx.x & 63;
  if (row >= nrows) return;
  size_t idx = (size_t)row * DDIM + lane;
  float x = in[idx];
  float s = x * x;
  s += __shfl_xor(s, 1);  s += __shfl_xor(s, 2);  s += __shfl_xor(s, 4);
  s += __shfl_xor(s, 8);  s += __shfl_xor(s, 16); s += __shfl_xor(s, 32);
  float scale = 1.0f / fmaxf(sqrtf(s), 1e-12f);
  unsigned short b = f2bf(x * scale);
  out[idx] = b;
  if (outT) outT[(size_t)lane * tstride + row] = b;
}

// Pass A, K-split: per wave 16 rows x KCHUNK codes -> partial rowsum + partial
// U = sum(e * cb), written non-atomically to per-chunk partial buffers.
__global__ __launch_bounds__(256) void passA_kernel(
    const unsigned short* __restrict__ Zn,   // [32768][64] bf16
    const unsigned short* __restrict__ Cb,   // [8192][64]  bf16
    const unsigned short* __restrict__ CbT,  // [64][8192]  bf16
    const float* __restrict__ tptr,
    float* __restrict__ Up,                  // [KSPLIT][32768][64] f32
    float* __restrict__ rsp) {               // [KSPLIT][32768]     f32
  __shared__ unsigned short etile[4][16 * 56];  // 112B rows: 2-way alias only
  const int tid = threadIdx.x;
  const int w  = tid >> 6;
  const int l  = tid & 63;
  const int g  = l >> 4;
  const int ml = l & 15;
  const int rb = blockIdx.x & 511;
  const int ks = blockIdx.x >> 9;
  const int m_base = rb * 64 + w * 16;
  const int k0 = ks * KCHUNK;
  const float T  = tptr[0];
  const float sc = 1.4426950408889634f / T;  // log2(e)/T

  const bf16x8* znrow = (const bf16x8*)(Zn + (size_t)(m_base + ml) * DDIM);
  const bf16x8 zn0 = znrow[g];
  const bf16x8 zn1 = znrow[4 + g];

  const f32x4 zero = {0.f, 0.f, 0.f, 0.f};
  f32x4 uacc[4] = {zero, zero, zero, zero};  // U^T[d=ds*16+g*4+r][m=ml]
  float rs = 0.f;

  for (int kc = k0; kc < k0 + KCHUNK; kc += 32) {
#pragma unroll
    for (int cs = 0; cs < 2; ++cs) {
      const bf16x8* cbrow = (const bf16x8*)(Cb + (size_t)(kc + cs * 16 + ml) * DDIM);
      f32x4 acc = __builtin_amdgcn_mfma_f32_16x16x32_bf16(cbrow[g], zn0, zero, 0, 0, 0);
      acc = __builtin_amdgcn_mfma_f32_16x16x32_bf16(cbrow[4 + g], zn1, acc, 0, 0, 0);
      bf16x4 ep;
#pragma unroll
      for (int r = 0; r < 4; ++r) {
        float e = exp2f((acc[r] - 1.0f) * sc);  // exp((sim-1)/T) <= 1
        rs += e;
        ep[r] = (short)f2bf(e);
      }
      *(bf16x4*)&etile[w][ml * 56 + cs * 16 + g * 4] = ep;
    }
    asm volatile("s_waitcnt lgkmcnt(0)" ::: "memory");  // same-wave LDS dep
    const bf16x8 ef = *(const bf16x8*)&etile[w][ml * 56 + g * 8];
#pragma unroll
    for (int ds = 0; ds < 4; ++ds) {
      const bf16x8 ct = *(const bf16x8*)(CbT + (size_t)(ds * 16 + ml) * KCODES + kc + g * 8);
      uacc[ds] = __builtin_amdgcn_mfma_f32_16x16x32_bf16(ct, ef, uacc[ds], 0, 0, 0);
    }
  }

  // partial rowsum for row m_base+ml
  rs += __shfl_xor(rs, 16);
  rs += __shfl_xor(rs, 32);
  if (g == 0) rsp[(size_t)ks * M_TOTAL + m_base + ml] = rs;

  // lanes cover disjoint (row, d): plain stores
  float* urow = Up + ((size_t)ks * M_TOTAL + m_base + ml) * DDIM;
#pragma unroll
  for (int ds = 0; ds < 4; ++ds)
    *(f32x4*)(urow + ds * 16 + g * 4) = uacc[ds];
}

// rs[m] = sum of KSPLIT partials
__global__ __launch_bounds__(256) void rs_kernel(
    const float* __restrict__ rsp, float* __restrict__ rs) {
  int m = blockIdx.x * 256 + threadIdx.x;
  float s = 0.f;
#pragma unroll
  for (int ks = 0; ks < KSPLIT; ++ks) s += rsp[(size_t)ks * M_TOTAL + m];
  rs[m] = s;
}

// z_q = (sum of U partials) / rs  (elementwise, vec4)
__global__ __launch_bounds__(256) void zq_kernel(
    const float* __restrict__ Up, const float* __restrict__ rs,
    float* __restrict__ zq) {
  size_t i = (size_t)blockIdx.x * 256 + threadIdx.x;  // one f32x4 per thread
  f32x4 u = *(const f32x4*)(Up + i * 4);
#pragma unroll
  for (int ks = 1; ks < KSPLIT; ++ks) {
    f32x4 p = *(const f32x4*)(Up + (size_t)ks * M_TOTAL * DDIM + i * 4);
#pragma unroll
    for (int r = 0; r < 4; ++r) u[r] += p[r];
  }
  float inv = 1.0f / rs[(i * 4) >> 6];
  f32x4 v = {u[0] * inv, u[1] * inv, u[2] * inv, u[3] * inv};
  *(f32x4*)(zq + i * 4) = v;
}

// Pass B, K-split: probs = exp((sim-1)/T) / rs, coalesced f32x4 stores.
__global__ __launch_bounds__(256) void probs_kernel(
    const unsigned short* __restrict__ Zn,
    const unsigned short* __restrict__ Cb,
    const float* __restrict__ tptr,
    const float* __restrict__ rsbuf,
    float* __restrict__ probs) {
  const int tid = threadIdx.x;
  const int w  = tid >> 6;
  const int l  = tid & 63;
  const int g  = l >> 4;
  const int ml = l & 15;
  const int rb = blockIdx.x & 511;
  const int ks = blockIdx.x >> 9;
  const int m_base = rb * 64 + w * 16;
  const int k0 = ks * KCHUNK;
  const float T  = tptr[0];
  const float sc = 1.4426950408889634f / T;

  const bf16x8* znrow = (const bf16x8*)(Zn + (size_t)(m_base + ml) * DDIM);
  const bf16x8 zn0 = znrow[g];
  const bf16x8 zn1 = znrow[4 + g];
  const float inv = 1.0f / rsbuf[m_base + ml];
  const f32x4 zero = {0.f, 0.f, 0.f, 0.f};

  float* prow = probs + (size_t)(m_base + ml) * KCODES;
  for (int kc = k0; kc < k0 + KCHUNK; kc += 32) {
    const bf16x8* cb0 = (const bf16x8*)(Cb + (size_t)(kc + ml) * DDIM);
    const bf16x8* cb1 = (const bf16x8*)(Cb + (size_t)(kc + 16 + ml) * DDIM);
    f32x4 a0 = __builtin_amdgcn_mfma_f32_16x16x32_bf16(cb0[g], zn0, zero, 0, 0, 0);
    a0 = __builtin_amdgcn_mfma_f32_16x16x32_bf16(cb0[4 + g], zn1, a0, 0, 0, 0);
    f32x4 a1 = __builtin_amdgcn_mfma_f32_16x16x32_bf16(cb1[g], zn0, zero, 0, 0, 0);
    a1 = __builtin_amdgcn_mfma_f32_16x16x32_bf16(cb1[4 + g], zn1, a1, 0, 0, 0);
    f32x4 p0, p1;
#pragma unroll
    for (int r = 0; r < 4; ++r) {
      p0[r] = exp2f((a0[r] - 1.0f) * sc) * inv;
      p1[r] = exp2f((a1[r] - 1.0f) * sc) * inv;
    }
    *(f32x4*)(prow + kc + g * 4) = p0;          // per row: 128B contiguous
    *(f32x4*)(prow + kc + 16 + g * 4) = p1;     // across the two tiles
  }
}

extern "C" void kernel_launch(void* const* d_in, const int* in_sizes, int n_in,
                              void* d_out, int out_size, void* d_ws, size_t ws_size,
                              hipStream_t stream) {
  const float* z    = (const float*)d_in[0];
  const float* emb  = (const float*)d_in[1];
  const float* temp = (const float*)d_in[2];

  float* probs = (float*)d_out;
  float* zq    = probs + (size_t)M_TOTAL * KCODES;

  unsigned short* Zn  = (unsigned short*)d_ws;              // 4 MB
  unsigned short* Cb  = Zn + (size_t)M_TOTAL * DDIM;        // 1 MB
  unsigned short* CbT = Cb + (size_t)KCODES * DDIM;         // 1 MB
  float* Up  = (float*)(CbT + (size_t)KCODES * DDIM);       // 32 MB
  float* rsp = Up + (size_t)KSPLIT * M_TOTAL * DDIM;        // 512 KB
  float* rs  = rsp + (size_t)KSPLIT * M_TOTAL;              // 128 KB

  norm_rows_kernel<<<M_TOTAL / 4, 256, 0, stream>>>(z, Zn, nullptr, M_TOTAL, 0);
  norm_rows_kernel<<<KCODES / 4, 256, 0, stream>>>(emb, Cb, CbT, KCODES, KCODES);
  passA_kernel<<<512 * KSPLIT, 256, 0, stream>>>(Zn, Cb, CbT, temp, Up, rsp);
  rs_kernel<<<M_TOTAL / 256, 256, 0, stream>>>(rsp, rs);
  zq_kernel<<<(M_TOTAL * DDIM / 4) / 256, 256, 0, stream>>>(Up, rs, zq);
  probs_kernel<<<512 * KSPLIT, 256, 0, stream>>>(Zn, Cb, temp, rs, probs);
}

// Round 4
// 378.090 us; speedup vs baseline: 2.4224x; 2.4224x over previous
//
#include <hip/hip_runtime.h>

// Quantizer: B=8, N=4096, D=64, K=8192
// probs = softmax(sim/T) over K;  z_q = probs @ codebook
// sim = l2norm(z) @ l2norm(emb)^T, sim in [-1,1] -> no online max needed.
// Round 4: R1-R3 all ~900us regardless of occupancy -> TCP line-throughput
// bound (every codebook load = 16-line scatter, L1-missing). Fix: fragment-
// interleaved global layouts + per-block LDS staging (coalesced 16B/thread,
// double-buffered) so codebook is read once per block, not once per wave.

#define M_TOTAL 32768   // B*N
#define KCODES  8192
#define DDIM    64
#define KSPLIT  4
#define KCHUNK  (KCODES / KSPLIT)   // 2048
#define M_ROWS  128                 // rows per block (8 waves x 16)

typedef __attribute__((ext_vector_type(8))) short bf16x8;
typedef __attribute__((ext_vector_type(4))) short bf16x4;
typedef __attribute__((ext_vector_type(4))) float f32x4;

__device__ inline unsigned short f2bf(float x) {
  union { float f; unsigned u; } v; v.f = x;
  unsigned r = v.u + 0x7FFFu + ((v.u >> 16) & 1u);  // RNE
  return (unsigned short)(r >> 16);
}

// One wave per row: L2-normalize, emit bf16 in MFMA-fragment-interleaved
// layout. Frag unit = 512 shorts (1KB). For A/B frags of 16x16x32:
//   F[(blk16*2+h)*512 + l*8 + j] = X[blk16*16 + (l&15)][h*32 + (l>>4)*8 + j]
// Optional transposed-frag copy (for U-pass A operand):
//   FT[(blk32*4+ds)*512 + l*8 + j] = X[blk32*32 + (l>>4)*8 + j][ds*16+(l&15)]
__global__ __launch_bounds__(256) void norm_rows_kernel(
    const float* __restrict__ in, unsigned short* __restrict__ F,
    unsigned short* __restrict__ FT, int nrows) {
  int row = blockIdx.x * 4 + (threadIdx.x >> 6);
  int d = threadIdx.x & 63;
  if (row >= nrows) return;
  float x = in[(size_t)row * DDIM + d];
  float s = x * x;
  s += __shfl_xor(s, 1);  s += __shfl_xor(s, 2);  s += __shfl_xor(s, 4);
  s += __shfl_xor(s, 8);  s += __shfl_xor(s, 16); s += __shfl_xor(s, 32);
  float scale = 1.0f / fmaxf(sqrtf(s), 1e-12f);
  unsigned short b = f2bf(x * scale);
  {
    int blk = row >> 4, ml = row & 15;
    int h = d >> 5, g = (d >> 3) & 3, j = d & 7;
    F[((size_t)(blk * 2 + h)) * 512 + (g * 16 + ml) * 8 + j] = b;
  }
  if (FT) {
    int ds = d >> 4, dl = d & 15;
    int kb = row >> 5, kg = (row >> 3) & 3, kj = row & 7;
    FT[((size_t)(kb * 4 + ds)) * 512 + (kg * 16 + dl) * 8 + kj] = b;
  }
}

// Pass A: 8 waves x 16 rows = 128 rows/block, K-chunk 2048, k-step 32.
// Per step: block stages 4KB FCb + 4KB FCbT into LDS (16B/thread, dbuf),
// waves compute sim -> exp -> E-frag (LDS round-trip) -> U MFMA.
__global__ __launch_bounds__(512, 4) void passA_kernel(
    const unsigned short* __restrict__ FZn,
    const unsigned short* __restrict__ FCb,
    const unsigned short* __restrict__ FCbT,
    const float* __restrict__ tptr,
    float* __restrict__ Up,                  // [KSPLIT][32768][64] f32
    float* __restrict__ rsp) {               // [KSPLIT][32768]     f32
  __shared__ __align__(16) unsigned short sbuf[2][4096];   // 2 x 8KB
  __shared__ __align__(16) unsigned short etile[8][16 * 56];
  const int tid = threadIdx.x;
  const int w  = tid >> 6, l = tid & 63, g = l >> 4, ml = l & 15;
  const int rb = blockIdx.x & 255;
  const int ks = blockIdx.x >> 8;
  const int m_base = rb * M_ROWS + w * 16;
  const int k0 = ks * KCHUNK;
  const float sc = 1.4426950408889634f / tptr[0];  // log2(e)/T

  // Zn fragments: coalesced (lane's own 16B slot)
  const unsigned short* fz = FZn + ((size_t)((rb * 8 + w) * 2)) * 512;
  const bf16x8 zn0 = *(const bf16x8*)(fz + l * 8);
  const bf16x8 zn1 = *(const bf16x8*)(fz + 512 + l * 8);

  const f32x4 zero = {0.f, 0.f, 0.f, 0.f};
  f32x4 uacc[4] = {zero, zero, zero, zero};
  float rs = 0.f;

  // staging: thread t copies 16B; FCb chunk (t<256) then FCbT chunk.
  // both have shorts-offset kc*64 for the tile starting at code kc.
  const unsigned short* gb = (tid < 256 ? FCb : FCbT) + (size_t)(tid & 255) * 8;
  bf16x8 stg = *(const bf16x8*)(gb + (size_t)k0 * 64);
  int cur = 0;

  const int NIT = KCHUNK / 32;  // 64
  for (int it = 0; it < NIT; ++it) {
    *(bf16x8*)&sbuf[cur][tid * 8] = stg;                 // waits vmcnt on stg
    if (it + 1 < NIT)
      stg = *(const bf16x8*)(gb + (size_t)(k0 + (it + 1) * 32) * 64);
    __syncthreads();
    const unsigned short* sb = &sbuf[cur][0];
#pragma unroll
    for (int cs = 0; cs < 2; ++cs) {
      const bf16x8 cb0 = *(const bf16x8*)(sb + (cs * 2 + 0) * 512 + l * 8);
      const bf16x8 cb1 = *(const bf16x8*)(sb + (cs * 2 + 1) * 512 + l * 8);
      f32x4 acc = __builtin_amdgcn_mfma_f32_16x16x32_bf16(cb0, zn0, zero, 0, 0, 0);
      acc = __builtin_amdgcn_mfma_f32_16x16x32_bf16(cb1, zn1, acc, 0, 0, 0);
      bf16x4 ep;
#pragma unroll
      for (int r = 0; r < 4; ++r) {
        float e = exp2f((acc[r] - 1.0f) * sc);  // exp((sim-1)/T) <= 1
        rs += e;
        ep[r] = (short)f2bf(e);
      }
      *(bf16x4*)&etile[w][ml * 56 + cs * 16 + g * 4] = ep;
    }
    asm volatile("s_waitcnt lgkmcnt(0)" ::: "memory");  // same-wave LDS dep
    const bf16x8 ef = *(const bf16x8*)&etile[w][ml * 56 + g * 8];
#pragma unroll
    for (int ds = 0; ds < 4; ++ds) {
      const bf16x8 ct = *(const bf16x8*)(sb + 2048 + ds * 512 + l * 8);
      uacc[ds] = __builtin_amdgcn_mfma_f32_16x16x32_bf16(ct, ef, uacc[ds], 0, 0, 0);
    }
    cur ^= 1;
  }

  rs += __shfl_xor(rs, 16);
  rs += __shfl_xor(rs, 32);
  if (g == 0) rsp[(size_t)ks * M_TOTAL + m_base + ml] = rs;

  float* urow = Up + ((size_t)ks * M_TOTAL + m_base + ml) * DDIM;
#pragma unroll
  for (int ds = 0; ds < 4; ++ds)
    *(f32x4*)(urow + ds * 16 + g * 4) = uacc[ds];
}

// rs[m] = sum of KSPLIT partials
__global__ __launch_bounds__(256) void rs_kernel(
    const float* __restrict__ rsp, float* __restrict__ rs) {
  int m = blockIdx.x * 256 + threadIdx.x;
  float s = 0.f;
#pragma unroll
  for (int ks = 0; ks < KSPLIT; ++ks) s += rsp[(size_t)ks * M_TOTAL + m];
  rs[m] = s;
}

// z_q = (sum of U partials) / rs
__global__ __launch_bounds__(256) void zq_kernel(
    const float* __restrict__ Up, const float* __restrict__ rs,
    float* __restrict__ zq) {
  size_t i = (size_t)blockIdx.x * 256 + threadIdx.x;
  f32x4 u = *(const f32x4*)(Up + i * 4);
#pragma unroll
  for (int ks = 1; ks < KSPLIT; ++ks) {
    f32x4 p = *(const f32x4*)(Up + (size_t)ks * M_TOTAL * DDIM + i * 4);
#pragma unroll
    for (int r = 0; r < 4; ++r) u[r] += p[r];
  }
  float inv = 1.0f / rs[(i * 4) >> 6];
  f32x4 v = {u[0] * inv, u[1] * inv, u[2] * inv, u[3] * inv};
  *(f32x4*)(zq + i * 4) = v;
}

// Pass B: 8 waves x 16 rows, K-chunk 2048, k-step 64 (8KB FCb staged, dbuf).
__global__ __launch_bounds__(512, 4) void probs_kernel(
    const unsigned short* __restrict__ FZn,
    const unsigned short* __restrict__ FCb,
    const float* __restrict__ tptr,
    const float* __restrict__ rsv,
    float* __restrict__ probs) {
  __shared__ __align__(16) unsigned short sbuf[2][4096];
  const int tid = threadIdx.x;
  const int w  = tid >> 6, l = tid & 63, g = l >> 4, ml = l & 15;
  const int rb = blockIdx.x & 255;
  const int ks = blockIdx.x >> 8;
  const int m_base = rb * M_ROWS + w * 16;
  const int k0 = ks * KCHUNK;
  const float sc = 1.4426950408889634f / tptr[0];

  const unsigned short* fz = FZn + ((size_t)((rb * 8 + w) * 2)) * 512;
  const bf16x8 zn0 = *(const bf16x8*)(fz + l * 8);
  const bf16x8 zn1 = *(const bf16x8*)(fz + 512 + l * 8);
  const float inv = 1.0f / rsv[m_base + ml];
  const f32x4 zero = {0.f, 0.f, 0.f, 0.f};
  float* prow = probs + (size_t)(m_base + ml) * KCODES;

  const unsigned short* gb = FCb + (size_t)tid * 8;  // 512 thr x 16B = 8KB/step
  bf16x8 stg = *(const bf16x8*)(gb + (size_t)k0 * 64);
  int cur = 0;

  const int NIT = KCHUNK / 64;  // 32
  for (int it = 0; it < NIT; ++it) {
    *(bf16x8*)&sbuf[cur][tid * 8] = stg;
    if (it + 1 < NIT)
      stg = *(const bf16x8*)(gb + (size_t)(k0 + (it + 1) * 64) * 64);
    __syncthreads();
    const unsigned short* sb = &sbuf[cur][0];
    const int kc = k0 + it * 64;
#pragma unroll
    for (int cb = 0; cb < 4; ++cb) {
      const bf16x8 c0 = *(const bf16x8*)(sb + (cb * 2 + 0) * 512 + l * 8);
      const bf16x8 c1 = *(const bf16x8*)(sb + (cb * 2 + 1) * 512 + l * 8);
      f32x4 a = __builtin_amdgcn_mfma_f32_16x16x32_bf16(c0, zn0, zero, 0, 0, 0);
      a = __builtin_amdgcn_mfma_f32_16x16x32_bf16(c1, zn1, a, 0, 0, 0);
      f32x4 p;
#pragma unroll
      for (int r = 0; r < 4; ++r) p[r] = exp2f((a[r] - 1.0f) * sc) * inv;
      *(f32x4*)(prow + kc + cb * 16 + g * 4) = p;
    }
    cur ^= 1;
  }
}

extern "C" void kernel_launch(void* const* d_in, const int* in_sizes, int n_in,
                              void* d_out, int out_size, void* d_ws, size_t ws_size,
                              hipStream_t stream) {
  const float* z    = (const float*)d_in[0];
  const float* emb  = (const float*)d_in[1];
  const float* temp = (const float*)d_in[2];

  float* probs = (float*)d_out;
  float* zq    = probs + (size_t)M_TOTAL * KCODES;

  unsigned short* FZn  = (unsigned short*)d_ws;             // 4 MB
  unsigned short* FCb  = FZn + (size_t)M_TOTAL * DDIM;      // 1 MB
  unsigned short* FCbT = FCb + (size_t)KCODES * DDIM;       // 1 MB
  float* Up  = (float*)(FCbT + (size_t)KCODES * DDIM);      // 32 MB
  float* rsp = Up + (size_t)KSPLIT * M_TOTAL * DDIM;        // 512 KB
  float* rs  = rsp + (size_t)KSPLIT * M_TOTAL;              // 128 KB

  norm_rows_kernel<<<M_TOTAL / 4, 256, 0, stream>>>(z, FZn, nullptr, M_TOTAL);
  norm_rows_kernel<<<KCODES / 4, 256, 0, stream>>>(emb, FCb, FCbT, KCODES);
  passA_kernel<<<256 * KSPLIT, 512, 0, stream>>>(FZn, FCb, FCbT, temp, Up, rsp);
  rs_kernel<<<M_TOTAL / 256, 256, 0, stream>>>(rsp, rs);
  zq_kernel<<<(M_TOTAL * DDIM / 4) / 256, 256, 0, stream>>>(Up, rs, zq);
  probs_kernel<<<256 * KSPLIT, 512, 0, stream>>>(FZn, FCb, temp, rs, probs);
}